// Round 5
// baseline (714.570 us; speedup 1.0000x reference)
//
#include <hip/hip_runtime.h>
#include <hip/hip_fp16.h>
#include <hip/hip_cooperative_groups.h>

namespace cg = cooperative_groups;

// LightGCN on MI355X. Gather formulation, dinv folded into data (y = dinv*x,
// fp16 128B rows). CSR built via LDS-staged two-phase binning.
// v5: SLOT-SPACE pipeline + cooperative mega-kernel.
//  - binB builds a degree-sorted slot permutation per bucket; offcnt, y-tables
//    and pairs are all SLOT-indexed -> offcnt/order reads coalesced, y writes
//    sequential; only mode-1's emb/out stay node-indexed.
//  - pairs (node ids) are translated node->slot by a small phase (islot table
//    is L2-resident) between binB and layer 1.
//  - binB + translate + 3 gather layers fused in ONE cooperative kernel with
//    grid.sync() -> 3 fewer dispatch boundaries.
//  - gather: 8 lanes/slot, 8 slots/wave, branchless 8-edge blocks (pad slot
//    with all-zero rows absorbs OOB loads), v_fma_mix fp16->fp32 accumulate.
//
// d_in[0]: edge_index int32 [2][1M]; d_in[1]: emb_weight fp32 [150000][64]
// d_out  : 150000x64 fp32

constexpr int kNodes     = 150000;
constexpr int kDim       = 64;
constexpr int kEdges     = 1000000;
constexpr int kBkt       = (kNodes + 255) / 256;     // 586 buckets
constexpr int kSlots     = kBkt * 256;               // 150016 slots
constexpr int kBktCap    = 2048;                     // mean 1707, +8.3 sigma
constexpr int kChunk     = 4096;                     // edges per binA block

typedef float  floatx4 __attribute__((ext_vector_type(4)));

__device__ __forceinline__ int wave_incl_scan(int v, int lane) {
    #pragma unroll
    for (int s = 1; s < 64; s <<= 1) {
        int u = __shfl_up(v, s);
        if (lane >= s) v += u;
    }
    return v;
}

// fp16 (packed in int bits) accumulated into fp32 in one VALU op.
#define ACC_LO(s, r) asm("v_fma_mix_f32 %0, %1, 1.0, %0 op_sel:[0,0,0] op_sel_hi:[1,0,0]" : "+v"(s) : "v"(r))
#define ACC_HI(s, r) asm("v_fma_mix_f32 %0, %1, 1.0, %0 op_sel:[1,0,0] op_sel_hi:[1,0,0]" : "+v"(s) : "v"(r))

#define ACC_ROW(rr) do { \
    ACC_LO(s0, rr.x); ACC_HI(s1, rr.x); \
    ACC_LO(s2, rr.y); ACC_HI(s3, rr.y); \
    ACC_LO(s4, rr.z); ACC_HI(s5, rr.z); \
    ACC_LO(s6, rr.w); ACC_HI(s7, rr.w); } while (0)

// ---------------- Phase A: bin edges by dst>>8, LDS-staged ----------------

__global__ __launch_bounds__(1024) void binA_kernel(const int* __restrict__ src,
                                                    const int* __restrict__ dst,
                                                    int* __restrict__ cur,     // [kBkt] zeroed
                                                    unsigned* __restrict__ bin) {
    __shared__ int hist[1024];
    __shared__ int cursor[1024];
    __shared__ int sexcl[1024];
    __shared__ int gstart[1024];
    __shared__ int wsum[16];
    __shared__ unsigned staged[kChunk];
    __shared__ unsigned short sbkt[kChunk];

    int t      = threadIdx.x;
    int lane   = t & 63;
    int w      = t >> 6;
    int chunk0 = blockIdx.x * kChunk;
    int n      = min(kChunk, kEdges - chunk0);

    hist[t] = 0;
    __syncthreads();

    int myb[4], myd[4];
    #pragma unroll
    for (int j = 0; j < 4; ++j) {
        int i = j * 1024 + t;
        if (i < n) {
            int d = dst[chunk0 + i];
            myb[j] = d >> 8;
            myd[j] = d & 255;
            atomicAdd(&hist[myb[j]], 1);
        } else myb[j] = -1;
    }
    __syncthreads();

    int c   = hist[t];
    int inc = wave_incl_scan(c, lane);
    if (lane == 63) wsum[w] = inc;
    __syncthreads();
    if (w == 0) {
        int v  = (lane < 16) ? wsum[lane] : 0;
        int sc = wave_incl_scan(v, lane);
        if (lane < 16) wsum[lane] = sc - v;
    }
    __syncthreads();
    int excl = wsum[w] + inc - c;
    sexcl[t]  = excl;
    cursor[t] = excl;
    if (t < kBkt) gstart[t] = atomicAdd(&cur[t], c);
    __syncthreads();

    #pragma unroll
    for (int j = 0; j < 4; ++j) {
        int i = j * 1024 + t;
        if (i < n) {
            int s = src[chunk0 + i];
            unsigned pk = ((unsigned)myd[j] << 24) | (unsigned)s;
            int p = atomicAdd(&cursor[myb[j]], 1);
            staged[p] = pk;
            sbkt[p]   = (unsigned short)myb[j];
        }
    }
    __syncthreads();

    #pragma unroll
    for (int j = 0; j < 4; ++j) {
        int i = j * 1024 + t;
        if (i < n) {
            int bu = sbkt[i];
            int gp = gstart[bu] + (i - sexcl[bu]);
            if (gp < kBktCap) bin[(size_t)bu * kBktCap + gp] = staged[i];
        }
    }
}

// ---------------- Phase B (device fn): CSR build + slot permutation + prescale ----

__device__ __forceinline__ void phaseB(int b,
                                       const int* __restrict__ cur,
                                       const unsigned* __restrict__ bin,
                                       int* __restrict__ pairs,
                                       int2* __restrict__ offcnt,   // slot-indexed
                                       int* __restrict__ order,     // slot -> node
                                       int* __restrict__ islot,     // node -> slot
                                       int* __restrict__ totalE,
                                       const float4* __restrict__ emb4,
                                       int4* __restrict__ y4) {     // slot-indexed
    __shared__ int lcnt[256];
    __shared__ int cursor[256];
    __shared__ int wsum[4];
    __shared__ int wred[4];
    __shared__ int chist[64];
    __shared__ int stage[kBktCap];
    __shared__ float sdinv[256];
    __shared__ int sslot[256];

    int t = threadIdx.x;
    int lane = t & 63, w = t >> 6;
    int cnt = min(cur[b], kBktCap);
    const unsigned* mybin = bin + (size_t)b * kBktCap;

    // fused scan_base: bs = sum_{j<b} min(cur[j], cap)
    {
        int acc = 0;
        for (int j = t; j < b; j += 256) acc += min(cur[j], kBktCap);
        #pragma unroll
        for (int s = 32; s; s >>= 1) acc += __shfl_down(acc, s);
        if (lane == 0) wred[w] = acc;
    }

    lcnt[t] = 0;
    if (t < 64) chist[t] = 0;
    __syncthreads();
    int bs = wred[0] + wred[1] + wred[2] + wred[3];

    for (int i = t; i < cnt; i += 256) atomicAdd(&lcnt[mybin[i] >> 24], 1);
    __syncthreads();

    int c   = lcnt[t];
    int inc = wave_incl_scan(c, lane);
    if (lane == 63) wsum[w] = inc;
    int cv = min(c, 63);
    atomicAdd(&chist[cv], 1);
    __syncthreads();

    if (t < 64) {
        int v  = chist[t];
        int sc = wave_incl_scan(v, lane);
        chist[t] = sc - v;                 // exclusive start -> becomes cursor
    }
    if (t == 0) {
        int a = 0;
        #pragma unroll
        for (int k = 0; k < 4; ++k) { int v = wsum[k]; wsum[k] = a; a += v; }
    }
    __syncthreads();
    int excl = wsum[w] + inc - c;

    int node = (b << 8) + t;
    float dv = (c > 0) ? rsqrtf((float)c) : 0.0f;
    sdinv[t] = dv;
    cursor[t] = excl;

    // counting-sort placement -> slot permutation
    int myslot = atomicAdd(&chist[cv], 1);
    sslot[t] = myslot;
    int gslot = (b << 8) + myslot;
    order[gslot]  = (node < kNodes) ? node : kNodes;
    offcnt[gslot] = make_int2(bs + excl, c);
    if (node <= kNodes) islot[node] = gslot;   // also anchors pad slot at kNodes
    if (b == kBkt - 1 && t == 0) *totalE = bs + cnt;
    __syncthreads();

    for (int i = t; i < cnt; i += 256) {
        unsigned v = mybin[i];
        int p = atomicAdd(&cursor[v >> 24], 1);
        stage[p] = (int)(v & 0x00FFFFFFu);
    }
    __syncthreads();
    for (int i = t; i < cnt; i += 256) pairs[bs + i] = stage[i];

    // fused prescale: y0[slot] = fp16(emb[node] * dinv); pad slots get zeros.
    #pragma unroll
    for (int k = 0; k < 8; ++k) {
        int idx   = (k << 8) + t;
        int nl    = idx >> 3;
        int qq    = idx & 7;
        int node2 = (b << 8) + nl;
        size_t gs = (size_t)((b << 8) + sslot[nl]);
        if (node2 < kNodes) {
            float d = sdinv[nl];
            size_t e = (size_t)node2 * 16 + (size_t)qq * 2;
            float4 v0 = emb4[e];
            float4 v1 = emb4[e + 1];
            __half2 p0 = __floats2half2_rn(v0.x * d, v0.y * d);
            __half2 p1 = __floats2half2_rn(v0.z * d, v0.w * d);
            __half2 p2 = __floats2half2_rn(v1.x * d, v1.y * d);
            __half2 p3 = __floats2half2_rn(v1.z * d, v1.w * d);
            int4 wv;
            wv.x = *reinterpret_cast<int*>(&p0); wv.y = *reinterpret_cast<int*>(&p1);
            wv.z = *reinterpret_cast<int*>(&p2); wv.w = *reinterpret_cast<int*>(&p3);
            y4[gs * 8 + qq] = wv;
        } else {
            int4 z; z.x = 0; z.y = 0; z.z = 0; z.w = 0;
            y4[gs * 8 + qq] = z;
        }
    }
}

// ---------------- gather layer (device fn): slot-space, grid-stride ----------------

__device__ __forceinline__ void gather_layer(const int2* __restrict__ offcnt,
                                             const int* __restrict__ order,
                                             const int* __restrict__ pairs,
                                             const __half* __restrict__ x16,
                                             __half* __restrict__ yOut,
                                             const float4* __restrict__ emb4,
                                             const __half* __restrict__ y1,
                                             const __half* __restrict__ y2,
                                             float* __restrict__ outf,
                                             int padslot, int mode) {
    int q    = threadIdx.x & 7;
    int lane = threadIdx.x & 63;
    int gb   = lane & 56;

    for (int blk = blockIdx.x; blk < (kSlots >> 5); blk += gridDim.x) {
        int slot = (blk << 5) + (threadIdx.x >> 3);

        int2 oc = offcnt[slot];               // coalesced (slot-consecutive)
        int b = oc.x, cnt = oc.y;

        float s0 = 0.f, s1 = 0.f, s2 = 0.f, s3 = 0.f,
              s4 = 0.f, s5 = 0.f, s6 = 0.f, s7 = 0.f;

        int mysrc = (q < cnt) ? pairs[b + q] : padslot;
        for (int base2 = 0; base2 < cnt; base2 += 8) {
            int np  = base2 + 8 + q;
            int nxt = (np < cnt) ? pairs[b + np] : padslot;

            int si0 = __shfl(mysrc, gb + 0);
            int si1 = __shfl(mysrc, gb + 1);
            int si2 = __shfl(mysrc, gb + 2);
            int si3 = __shfl(mysrc, gb + 3);
            int si4 = __shfl(mysrc, gb + 4);
            int si5 = __shfl(mysrc, gb + 5);
            int si6 = __shfl(mysrc, gb + 6);
            int si7 = __shfl(mysrc, gb + 7);
            int4 r0 = *(const int4*)(x16 + ((size_t)si0 << 6) + (q << 3));
            int4 r1 = *(const int4*)(x16 + ((size_t)si1 << 6) + (q << 3));
            int4 r2 = *(const int4*)(x16 + ((size_t)si2 << 6) + (q << 3));
            int4 r3 = *(const int4*)(x16 + ((size_t)si3 << 6) + (q << 3));
            int4 r4 = *(const int4*)(x16 + ((size_t)si4 << 6) + (q << 3));
            int4 r5 = *(const int4*)(x16 + ((size_t)si5 << 6) + (q << 3));
            int4 r6 = *(const int4*)(x16 + ((size_t)si6 << 6) + (q << 3));
            int4 r7 = *(const int4*)(x16 + ((size_t)si7 << 6) + (q << 3));
            ACC_ROW(r0); ACC_ROW(r1); ACC_ROW(r2); ACC_ROW(r3);
            ACC_ROW(r4); ACC_ROW(r5); ACC_ROW(r6); ACC_ROW(r7);
            mysrc = nxt;
        }

        if (mode == 0) {
            float dvv = (cnt > 0) ? rsqrtf((float)cnt) : 0.0f;
            float dv2 = dvv * dvv;
            __half2 p0 = __floats2half2_rn(s0 * dv2, s1 * dv2);
            __half2 p1 = __floats2half2_rn(s2 * dv2, s3 * dv2);
            __half2 p2 = __floats2half2_rn(s4 * dv2, s5 * dv2);
            __half2 p3 = __floats2half2_rn(s6 * dv2, s7 * dv2);
            int4 wv;
            wv.x = *reinterpret_cast<int*>(&p0); wv.y = *reinterpret_cast<int*>(&p1);
            wv.z = *reinterpret_cast<int*>(&p2); wv.w = *reinterpret_cast<int*>(&p3);
            ((int4*)(yOut + ((size_t)slot << 6)))[q] = wv;   // sequential-ish
        } else {
            int node = order[slot];           // coalesced
            if (node < kNodes) {
                float dvv = (cnt > 0) ? rsqrtf((float)cnt) : 0.0f;
                float sq  = sqrtf((float)cnt);
                int4 r1 = ((const int4*)(y1 + ((size_t)slot << 6)))[q];
                int4 r2 = ((const int4*)(y2 + ((size_t)slot << 6)))[q];
                size_t i4 = (size_t)node * 16 + (size_t)q * 2;
                float4 e0 = emb4[i4];
                float4 e1 = emb4[i4 + 1];
                float2 a0 = __half22float2(*reinterpret_cast<__half2*>(&r1.x));
                float2 a1 = __half22float2(*reinterpret_cast<__half2*>(&r1.y));
                float2 a2 = __half22float2(*reinterpret_cast<__half2*>(&r1.z));
                float2 a3 = __half22float2(*reinterpret_cast<__half2*>(&r1.w));
                float2 c0 = __half22float2(*reinterpret_cast<__half2*>(&r2.x));
                float2 c1 = __half22float2(*reinterpret_cast<__half2*>(&r2.y));
                float2 c2 = __half22float2(*reinterpret_cast<__half2*>(&r2.z));
                float2 c3 = __half22float2(*reinterpret_cast<__half2*>(&r2.w));
                floatx4 o0, o1;
                o0.x = (e0.x + (a0.x + c0.x) * sq + s0 * dvv) * 0.25f;
                o0.y = (e0.y + (a0.y + c0.y) * sq + s1 * dvv) * 0.25f;
                o0.z = (e0.z + (a1.x + c1.x) * sq + s2 * dvv) * 0.25f;
                o0.w = (e0.w + (a1.y + c1.y) * sq + s3 * dvv) * 0.25f;
                o1.x = (e1.x + (a2.x + c2.x) * sq + s4 * dvv) * 0.25f;
                o1.y = (e1.y + (a2.y + c2.y) * sq + s5 * dvv) * 0.25f;
                o1.z = (e1.z + (a3.x + c3.x) * sq + s6 * dvv) * 0.25f;
                o1.w = (e1.w + (a3.y + c3.y) * sq + s7 * dvv) * 0.25f;
                floatx4* op = (floatx4*)(outf + i4 * 4);
                __builtin_nontemporal_store(o0, op);
                __builtin_nontemporal_store(o1, op + 1);
            }
        }
    }
}

// ---------------- cooperative mega-kernel: binB + translate + 3 layers ----------------

__global__ __launch_bounds__(256, 8) void mega_kernel(const int* __restrict__ cur,
                                                      const unsigned* __restrict__ bin,
                                                      int* __restrict__ pairs,
                                                      int2* __restrict__ offcnt,
                                                      int* __restrict__ order,
                                                      int* __restrict__ islot,
                                                      int* __restrict__ totalE,
                                                      const float4* __restrict__ emb4,
                                                      int4* __restrict__ y0,
                                                      __half* __restrict__ yA,
                                                      __half* __restrict__ yB,
                                                      float* __restrict__ outf) {
    cg::grid_group grid = cg::this_grid();

    for (int b = blockIdx.x; b < kBkt; b += gridDim.x)
        phaseB(b, cur, bin, pairs, offcnt, order, islot, totalE, emb4, y0);
    grid.sync();

    // translate pairs: node id -> slot id (islot is small, L2-resident)
    int E = *totalE;
    int padslot = islot[kNodes];
    for (int i = blockIdx.x * 256 + threadIdx.x; i < E; i += gridDim.x * 256)
        pairs[i] = islot[pairs[i]];
    grid.sync();

    const __half* y0h = (const __half*)y0;
    gather_layer(offcnt, order, pairs, y0h, yA, nullptr, nullptr, nullptr, nullptr,
                 padslot, 0);
    grid.sync();
    gather_layer(offcnt, order, pairs, yA, yB, nullptr, nullptr, nullptr, nullptr,
                 padslot, 0);
    grid.sync();
    gather_layer(offcnt, order, pairs, yB, nullptr, emb4, yA, yB, outf,
                 padslot, 1);
}

// ---------------- launch ----------------

extern "C" void kernel_launch(void* const* d_in, const int* in_sizes, int n_in,
                              void* d_out, int out_size, void* d_ws, size_t ws_size,
                              hipStream_t stream) {
    const int*   edge  = (const int*)d_in[0];
    const int*   src   = edge;
    const int*   dst   = edge + kEdges;
    const float* emb_w = (const float*)d_in[1];
    float*       out   = (float*)d_out;

    // Workspace layout (re-poisoned 0xAA each call), yA aliases bin (bin is
    // dead after phaseB; yA first written in layer 1, after a grid.sync):
    //   cur     : @0          4,096
    //   totalE  : @4096       128
    //   islot   : @4224       600,064  ((kNodes+1) ints)
    //   order   : @604288     600,064  (kSlots ints)
    //   offcnt  : @1204352    1,200,128 (kSlots int2)
    //   pairs   : @2404480    4,000,000
    //   y0      : @6404480    19,202,048 (kSlots fp16 rows)
    //   yB      : @25606528   19,202,048
    //   bin/yA  : @44808576   19,202,048 (union; bin = 4,800,512)  end 64,010,624
    char*     ws     = (char*)d_ws;
    int*      cur    = (int*)(ws);
    int*      totalE = (int*)(ws + 4096);
    int*      islot  = (int*)(ws + 4224);
    int*      order  = (int*)(ws + 604288);
    int2*     offcnt = (int2*)(ws + 1204352);
    int*      pairs  = (int*)(ws + 2404480);
    int4*     y0     = (int4*)(ws + 6404480);
    __half*   yB     = (__half*)(ws + 25606528);
    unsigned* bin    = (unsigned*)(ws + 44808576);
    __half*   yA     = (__half*)(ws + 44808576);

    const int binABlocks = (kEdges + kChunk - 1) / kChunk;   // 245

    static int coopGrid = 0;
    if (coopGrid == 0) {
        int nb = 0;
        (void)hipOccupancyMaxActiveBlocksPerMultiprocessor(&nb, mega_kernel, 256, 0);
        if (nb < 1) nb = 1;
        long g = (long)nb * 256;                             // 256 CUs on MI355X
        if (g > (kSlots >> 5)) g = (kSlots >> 5);            // 4688 chunks max
        coopGrid = (int)g;
    }

    (void)hipMemsetAsync(cur, 0, (size_t)kBkt * 4, stream);
    binA_kernel<<<binABlocks, 1024, 0, stream>>>(src, dst, cur, bin);

    const float4* emb4 = (const float4*)emb_w;
    void* margs[] = { (void*)&cur, (void*)&bin, (void*)&pairs, (void*)&offcnt,
                      (void*)&order, (void*)&islot, (void*)&totalE, (void*)&emb4,
                      (void*)&y0, (void*)&yA, (void*)&yB, (void*)&out };
    (void)hipLaunchCooperativeKernel(mega_kernel, dim3(coopGrid), dim3(256),
                                     margs, 0, stream);
}

// Round 6
// 281.259 us; speedup vs baseline: 2.5406x; 2.5406x over previous
//
#include <hip/hip_runtime.h>
#include <hip/hip_fp16.h>

// LightGCN on MI355X. Gather formulation, dinv folded into data (y = dinv*x,
// fp16 128B rows). CSR built via LDS-staged two-phase binning.
// v6: v4's multi-dispatch structure + SLOT-SPACE gather.
//  - binB builds a degree-sorted slot permutation per bucket; offcnt, y-tables
//    are SLOT-indexed -> offcnt reads coalesced, mode-0 y writes sequential,
//    mode-1 y1/y2 reads sequential. emb/out stay node-indexed (bucket-local).
//  - pairs (node ids) are translated node->slot by a tiny dispatch (islot is
//    L2-resident).
//  - dedicated all-zero row at slot kSlots in y0/yA/yB absorbs OOB edge-slot
//    padding loads (branchless 8-edge blocks).
//  - gather: 8 lanes/slot, 8 slots/wave, v_fma_mix fp16->fp32 accumulate.
//
// d_in[0]: edge_index int32 [2][1M]; d_in[1]: emb_weight fp32 [150000][64]
// d_out  : 150000x64 fp32

constexpr int kNodes     = 150000;
constexpr int kDim       = 64;
constexpr int kEdges     = 1000000;
constexpr int kBkt       = (kNodes + 255) / 256;     // 586 buckets
constexpr int kSlots     = kBkt * 256;               // 150016 slots
constexpr int kBktCap    = 2048;                     // mean 1707, +8.3 sigma
constexpr int kChunk     = 4096;                     // edges per binA block

typedef float  floatx4 __attribute__((ext_vector_type(4)));

__device__ __forceinline__ int wave_incl_scan(int v, int lane) {
    #pragma unroll
    for (int s = 1; s < 64; s <<= 1) {
        int u = __shfl_up(v, s);
        if (lane >= s) v += u;
    }
    return v;
}

// fp16 (packed in int bits) accumulated into fp32 in one VALU op.
#define ACC_LO(s, r) asm("v_fma_mix_f32 %0, %1, 1.0, %0 op_sel:[0,0,0] op_sel_hi:[1,0,0]" : "+v"(s) : "v"(r))
#define ACC_HI(s, r) asm("v_fma_mix_f32 %0, %1, 1.0, %0 op_sel:[1,0,0] op_sel_hi:[1,0,0]" : "+v"(s) : "v"(r))

#define ACC_ROW(rr) do { \
    ACC_LO(s0, rr.x); ACC_HI(s1, rr.x); \
    ACC_LO(s2, rr.y); ACC_HI(s3, rr.y); \
    ACC_LO(s4, rr.z); ACC_HI(s5, rr.z); \
    ACC_LO(s6, rr.w); ACC_HI(s7, rr.w); } while (0)

// ---------------- Phase A: bin edges by dst>>8, LDS-staged ----------------

__global__ __launch_bounds__(1024) void binA_kernel(const int* __restrict__ src,
                                                    const int* __restrict__ dst,
                                                    int* __restrict__ cur,     // [kBkt] zeroed
                                                    unsigned* __restrict__ bin) {
    __shared__ int hist[1024];
    __shared__ int cursor[1024];
    __shared__ int sexcl[1024];
    __shared__ int gstart[1024];
    __shared__ int wsum[16];
    __shared__ unsigned staged[kChunk];
    __shared__ unsigned short sbkt[kChunk];

    int t      = threadIdx.x;
    int lane   = t & 63;
    int w      = t >> 6;
    int chunk0 = blockIdx.x * kChunk;
    int n      = min(kChunk, kEdges - chunk0);

    hist[t] = 0;
    __syncthreads();

    int myb[4], myd[4];
    #pragma unroll
    for (int j = 0; j < 4; ++j) {
        int i = j * 1024 + t;
        if (i < n) {
            int d = dst[chunk0 + i];
            myb[j] = d >> 8;
            myd[j] = d & 255;
            atomicAdd(&hist[myb[j]], 1);
        } else myb[j] = -1;
    }
    __syncthreads();

    int c   = hist[t];
    int inc = wave_incl_scan(c, lane);
    if (lane == 63) wsum[w] = inc;
    __syncthreads();
    if (w == 0) {
        int v  = (lane < 16) ? wsum[lane] : 0;
        int sc = wave_incl_scan(v, lane);
        if (lane < 16) wsum[lane] = sc - v;
    }
    __syncthreads();
    int excl = wsum[w] + inc - c;
    sexcl[t]  = excl;
    cursor[t] = excl;
    if (t < kBkt) gstart[t] = atomicAdd(&cur[t], c);
    __syncthreads();

    #pragma unroll
    for (int j = 0; j < 4; ++j) {
        int i = j * 1024 + t;
        if (i < n) {
            int s = src[chunk0 + i];
            unsigned pk = ((unsigned)myd[j] << 24) | (unsigned)s;
            int p = atomicAdd(&cursor[myb[j]], 1);
            staged[p] = pk;
            sbkt[p]   = (unsigned short)myb[j];
        }
    }
    __syncthreads();

    #pragma unroll
    for (int j = 0; j < 4; ++j) {
        int i = j * 1024 + t;
        if (i < n) {
            int bu = sbkt[i];
            int gp = gstart[bu] + (i - sexcl[bu]);
            if (gp < kBktCap) bin[(size_t)bu * kBktCap + gp] = staged[i];
        }
    }
}

// ---------------- Phase B: CSR build + slot permutation + prescale ----------------
// Per bucket: counts, degree-sorted slot permutation, offcnt[slot], order[slot],
// islot[node], pairs (node ids), prescale y0[slot] = fp16(emb[node]*dinv).
// Block 0 also writes the dedicated zero row at slot kSlots in y0/yA/yB.

__global__ __launch_bounds__(256) void binB_kernel(const int* __restrict__ cur,
                                                   const unsigned* __restrict__ bin,
                                                   int* __restrict__ pairs,
                                                   int2* __restrict__ offcnt,
                                                   int* __restrict__ order,
                                                   int* __restrict__ islot,
                                                   int* __restrict__ totalE,
                                                   const float4* __restrict__ emb4,
                                                   int4* __restrict__ y4,
                                                   int4* __restrict__ yA4,
                                                   int4* __restrict__ yB4) {
    __shared__ int lcnt[256];
    __shared__ int cursor[256];
    __shared__ int wsum[4];
    __shared__ int wred[4];
    __shared__ int chist[64];
    __shared__ int stage[kBktCap];
    __shared__ float sdinv[256];
    __shared__ int sslot[256];

    int b = blockIdx.x;
    int t = threadIdx.x;
    int lane = t & 63, w = t >> 6;
    int cnt = min(cur[b], kBktCap);
    const unsigned* mybin = bin + (size_t)b * kBktCap;

    // fused scan_base: bs = sum_{j<b} min(cur[j], cap)
    {
        int acc = 0;
        for (int j = t; j < b; j += 256) acc += min(cur[j], kBktCap);
        #pragma unroll
        for (int s = 32; s; s >>= 1) acc += __shfl_down(acc, s);
        if (lane == 0) wred[w] = acc;
    }

    lcnt[t] = 0;
    if (t < 64) chist[t] = 0;
    __syncthreads();
    int bs = wred[0] + wred[1] + wred[2] + wred[3];

    for (int i = t; i < cnt; i += 256) atomicAdd(&lcnt[mybin[i] >> 24], 1);
    __syncthreads();

    int c   = lcnt[t];
    int inc = wave_incl_scan(c, lane);
    if (lane == 63) wsum[w] = inc;
    int cv = min(c, 63);
    atomicAdd(&chist[cv], 1);
    __syncthreads();

    if (t < 64) {
        int v  = chist[t];
        int sc = wave_incl_scan(v, lane);
        chist[t] = sc - v;                 // exclusive start -> becomes cursor
    }
    if (t == 0) {
        int a = 0;
        #pragma unroll
        for (int k = 0; k < 4; ++k) { int v = wsum[k]; wsum[k] = a; a += v; }
    }
    __syncthreads();
    int excl = wsum[w] + inc - c;

    int node = (b << 8) + t;
    float dv = (c > 0) ? rsqrtf((float)c) : 0.0f;
    sdinv[t] = dv;
    cursor[t] = excl;

    // counting-sort placement -> slot permutation
    int myslot = atomicAdd(&chist[cv], 1);
    sslot[t] = myslot;
    int gslot = (b << 8) + myslot;
    order[gslot]  = (node < kNodes) ? node : kNodes;
    offcnt[gslot] = make_int2(bs + excl, c);
    if (node < kNodes) islot[node] = gslot;
    if (b == kBkt - 1 && t == 0) *totalE = bs + cnt;
    __syncthreads();

    for (int i = t; i < cnt; i += 256) {
        unsigned v = mybin[i];
        int p = atomicAdd(&cursor[v >> 24], 1);
        stage[p] = (int)(v & 0x00FFFFFFu);
    }
    __syncthreads();
    for (int i = t; i < cnt; i += 256) pairs[bs + i] = stage[i];

    // fused prescale: y0[slot] = fp16(emb[node]*dinv); pad slots get zeros.
    #pragma unroll
    for (int k = 0; k < 8; ++k) {
        int idx   = (k << 8) + t;
        int nl    = idx >> 3;
        int qq    = idx & 7;
        int node2 = (b << 8) + nl;
        size_t gs = (size_t)((b << 8) + sslot[nl]);
        if (node2 < kNodes) {
            float d = sdinv[nl];
            size_t e = (size_t)node2 * 16 + (size_t)qq * 2;
            float4 v0 = emb4[e];
            float4 v1 = emb4[e + 1];
            __half2 p0 = __floats2half2_rn(v0.x * d, v0.y * d);
            __half2 p1 = __floats2half2_rn(v0.z * d, v0.w * d);
            __half2 p2 = __floats2half2_rn(v1.x * d, v1.y * d);
            __half2 p3 = __floats2half2_rn(v1.z * d, v1.w * d);
            int4 wv;
            wv.x = *reinterpret_cast<int*>(&p0); wv.y = *reinterpret_cast<int*>(&p1);
            wv.z = *reinterpret_cast<int*>(&p2); wv.w = *reinterpret_cast<int*>(&p3);
            y4[gs * 8 + qq] = wv;
        } else {
            y4[gs * 8 + qq] = make_int4(0, 0, 0, 0);
        }
    }

    // dedicated zero row at slot kSlots for all three y-tables
    if (b == 0 && t < 8) {
        int4 z = make_int4(0, 0, 0, 0);
        y4 [(size_t)kSlots * 8 + t] = z;
        yA4[(size_t)kSlots * 8 + t] = z;
        yB4[(size_t)kSlots * 8 + t] = z;
    }
}

// ---------------- translate: pairs node-id -> slot-id ----------------

__global__ __launch_bounds__(256) void translate_kernel(int* __restrict__ pairs,
                                                        const int* __restrict__ islot,
                                                        const int* __restrict__ totalE) {
    int E = *totalE;
    int i = blockIdx.x * 1024 + threadIdx.x;
    #pragma unroll
    for (int j = 0; j < 4; ++j, i += 256)
        if (i < E) pairs[i] = islot[pairs[i]];
}

// ---------------- gather layer: slot-space, 8 lanes/slot, 8 slots/wave ----------------
// Per 8-edge block: all 8 row loads issued back-to-back (dummy slots -> zero
// row at slot kSlots), then 64 unconditional v_fma_mix accumulates.
// mode 0: yOut[slot] = fp16(dinv^2 * s)        (layers 1,2; covers pad slots too)
// mode 1: out[node] = (emb + (y1+y2)*sqrt(cnt) + dinv*s) * 0.25   (layer 3)

__global__ __launch_bounds__(256) void gather_kernel(const int2* __restrict__ offcnt,
                                                     const int* __restrict__ order,
                                                     const int* __restrict__ pairs,
                                                     const __half* __restrict__ x16,
                                                     __half* __restrict__ yOut,
                                                     const float4* __restrict__ emb4,
                                                     const __half* __restrict__ y1,
                                                     const __half* __restrict__ y2,
                                                     float* __restrict__ outf,
                                                     int mode) {
    int t    = blockIdx.x * 256 + threadIdx.x;
    int slot = t >> 3;                    // 0 .. kSlots-1 (grid exact)
    int q    = t & 7;
    int lane = threadIdx.x & 63;
    int gb   = lane & 56;                 // first lane of my group

    int2 oc = offcnt[slot];               // coalesced (slot-consecutive)
    int b = oc.x, cnt = oc.y;

    float s0 = 0.f, s1 = 0.f, s2 = 0.f, s3 = 0.f,
          s4 = 0.f, s5 = 0.f, s6 = 0.f, s7 = 0.f;

    // lane q holds edge (base+q)'s src slot; broadcast within group via shfl.
    // OOB slots hold kSlots -> zero row, so the 8-block is branchless.
    int mysrc = (q < cnt) ? pairs[b + q] : kSlots;
    for (int base2 = 0; base2 < cnt; base2 += 8) {
        int np  = base2 + 8 + q;
        int nxt = (np < cnt) ? pairs[b + np] : kSlots;   // prefetch next block

        int si0 = __shfl(mysrc, gb + 0);
        int si1 = __shfl(mysrc, gb + 1);
        int si2 = __shfl(mysrc, gb + 2);
        int si3 = __shfl(mysrc, gb + 3);
        int si4 = __shfl(mysrc, gb + 4);
        int si5 = __shfl(mysrc, gb + 5);
        int si6 = __shfl(mysrc, gb + 6);
        int si7 = __shfl(mysrc, gb + 7);
        int4 r0 = *(const int4*)(x16 + ((size_t)si0 << 6) + (q << 3));
        int4 r1 = *(const int4*)(x16 + ((size_t)si1 << 6) + (q << 3));
        int4 r2 = *(const int4*)(x16 + ((size_t)si2 << 6) + (q << 3));
        int4 r3 = *(const int4*)(x16 + ((size_t)si3 << 6) + (q << 3));
        int4 r4 = *(const int4*)(x16 + ((size_t)si4 << 6) + (q << 3));
        int4 r5 = *(const int4*)(x16 + ((size_t)si5 << 6) + (q << 3));
        int4 r6 = *(const int4*)(x16 + ((size_t)si6 << 6) + (q << 3));
        int4 r7 = *(const int4*)(x16 + ((size_t)si7 << 6) + (q << 3));
        ACC_ROW(r0); ACC_ROW(r1); ACC_ROW(r2); ACC_ROW(r3);
        ACC_ROW(r4); ACC_ROW(r5); ACC_ROW(r6); ACC_ROW(r7);
        mysrc = nxt;
    }

    if (mode == 0) {
        float dvv = (cnt > 0) ? rsqrtf((float)cnt) : 0.0f;
        float dv2 = dvv * dvv;
        __half2 p0 = __floats2half2_rn(s0 * dv2, s1 * dv2);
        __half2 p1 = __floats2half2_rn(s2 * dv2, s3 * dv2);
        __half2 p2 = __floats2half2_rn(s4 * dv2, s5 * dv2);
        __half2 p3 = __floats2half2_rn(s6 * dv2, s7 * dv2);
        int4 wv;
        wv.x = *reinterpret_cast<int*>(&p0); wv.y = *reinterpret_cast<int*>(&p1);
        wv.z = *reinterpret_cast<int*>(&p2); wv.w = *reinterpret_cast<int*>(&p3);
        ((int4*)(yOut + ((size_t)slot << 6)))[q] = wv;   // sequential
    } else {
        int node = order[slot];               // coalesced
        if (node < kNodes) {
            float dvv = (cnt > 0) ? rsqrtf((float)cnt) : 0.0f;
            float sq  = sqrtf((float)cnt);    // = 1/dinv (0 if deg 0)
            int4 r1 = ((const int4*)(y1 + ((size_t)slot << 6)))[q];   // sequential
            int4 r2 = ((const int4*)(y2 + ((size_t)slot << 6)))[q];   // sequential
            size_t i4 = (size_t)node * 16 + (size_t)q * 2;
            float4 e0 = emb4[i4];
            float4 e1 = emb4[i4 + 1];
            float2 a0 = __half22float2(*reinterpret_cast<__half2*>(&r1.x));
            float2 a1 = __half22float2(*reinterpret_cast<__half2*>(&r1.y));
            float2 a2 = __half22float2(*reinterpret_cast<__half2*>(&r1.z));
            float2 a3 = __half22float2(*reinterpret_cast<__half2*>(&r1.w));
            float2 c0 = __half22float2(*reinterpret_cast<__half2*>(&r2.x));
            float2 c1 = __half22float2(*reinterpret_cast<__half2*>(&r2.y));
            float2 c2 = __half22float2(*reinterpret_cast<__half2*>(&r2.z));
            float2 c3 = __half22float2(*reinterpret_cast<__half2*>(&r2.w));
            floatx4 o0, o1;
            o0.x = (e0.x + (a0.x + c0.x) * sq + s0 * dvv) * 0.25f;
            o0.y = (e0.y + (a0.y + c0.y) * sq + s1 * dvv) * 0.25f;
            o0.z = (e0.z + (a1.x + c1.x) * sq + s2 * dvv) * 0.25f;
            o0.w = (e0.w + (a1.y + c1.y) * sq + s3 * dvv) * 0.25f;
            o1.x = (e1.x + (a2.x + c2.x) * sq + s4 * dvv) * 0.25f;
            o1.y = (e1.y + (a2.y + c2.y) * sq + s5 * dvv) * 0.25f;
            o1.z = (e1.z + (a3.x + c3.x) * sq + s6 * dvv) * 0.25f;
            o1.w = (e1.w + (a3.y + c3.y) * sq + s7 * dvv) * 0.25f;
            floatx4* op = (floatx4*)(outf + i4 * 4);
            __builtin_nontemporal_store(o0, op);
            __builtin_nontemporal_store(o1, op + 1);
        }
    }
}

// ---------------- launch ----------------

extern "C" void kernel_launch(void* const* d_in, const int* in_sizes, int n_in,
                              void* d_out, int out_size, void* d_ws, size_t ws_size,
                              hipStream_t stream) {
    const int*   edge  = (const int*)d_in[0];
    const int*   src   = edge;
    const int*   dst   = edge + kEdges;
    const float* emb_w = (const float*)d_in[1];
    float*       out   = (float*)d_out;

    // Workspace layout (re-poisoned 0xAA each call):
    //   cur     : @0          4,096
    //   totalE  : @4096       128
    //   islot   : @4224       600,000  (kNodes ints)
    //   order   : @604224     600,064  (kSlots ints)
    //   offcnt  : @1204288    1,200,128 (kSlots int2)
    //   pairs   : @2404416    4,000,000
    //   bin     : @6404416    4,800,512 (586*2048*4)
    //   y0      : @11204928   19,202,176 (kSlots+1 fp16 rows; last = zero row)
    //   yA      : @30407104   19,202,176
    //   yB      : @49609280   19,202,176   (end ~68.8 MB)
    char*     ws     = (char*)d_ws;
    int*      cur    = (int*)(ws);
    int*      totalE = (int*)(ws + 4096);
    int*      islot  = (int*)(ws + 4224);
    int*      order  = (int*)(ws + 604224);
    int2*     offcnt = (int2*)(ws + 1204288);
    int*      pairs  = (int*)(ws + 2404416);
    unsigned* bin    = (unsigned*)(ws + 6404416);
    __half*   y0     = (__half*)(ws + 11204928);
    __half*   yA     = (__half*)(ws + 30407104);
    __half*   yB     = (__half*)(ws + 49609280);

    const int binABlocks = (kEdges + kChunk - 1) / kChunk;   // 245
    const int transBlks  = (kEdges + 1023) / 1024;           // 977
    const int gatherBlks = (kSlots * 8) / 256;               // 4688, exact

    (void)hipMemsetAsync(cur, 0, (size_t)kBkt * 4, stream);
    binA_kernel<<<binABlocks, 1024, 0, stream>>>(src, dst, cur, bin);
    binB_kernel<<<kBkt, 256, 0, stream>>>(cur, bin, pairs, offcnt, order, islot,
                                          totalE, (const float4*)emb_w,
                                          (int4*)y0, (int4*)yA, (int4*)yB);
    translate_kernel<<<transBlks, 256, 0, stream>>>(pairs, islot, totalE);

    // Layer 1: yA = fp16(dinv^2 * sum y0[src])
    gather_kernel<<<gatherBlks, 256, 0, stream>>>(offcnt, order, pairs, y0,
                                                  yA, nullptr, nullptr, nullptr,
                                                  nullptr, 0);
    // Layer 2: yB = fp16(dinv^2 * sum yA[src])
    gather_kernel<<<gatherBlks, 256, 0, stream>>>(offcnt, order, pairs, yA,
                                                  yB, nullptr, nullptr, nullptr,
                                                  nullptr, 0);
    // Layer 3: out = (emb + h1 + h2 + h3)/4
    gather_kernel<<<gatherBlks, 256, 0, stream>>>(offcnt, order, pairs, yB,
                                                  nullptr, (const float4*)emb_w,
                                                  yA, yB, out, 1);
}